// Round 7
// baseline (355.178 us; speedup 1.0000x reference)
//
#include <hip/hip_runtime.h>

#define DEV __device__ __forceinline__

typedef float f32x4 __attribute__((ext_vector_type(4)));
typedef short s16x8 __attribute__((ext_vector_type(8)));
typedef unsigned short u16;
typedef unsigned int u32;

constexpr int Bb = 2, Tt = 2048, DIMc = 1024, Hh = 8, Ee = 5, Dd = 64;
constexpr int NTOK = Bb * Tt;   // 4096
constexpr int NQ = Hh * Ee * Dd; // 2560

DEV u16 f2bf(float f) {
  union { float f; u32 u; } v; v.f = f;
  u32 r = v.u + 0x7fffu + ((v.u >> 16) & 1u);
  return (u16)(r >> 16);
}

DEV u32 pk2(float a, float b) {  // two f32 -> packed bf16 pair (a=lo, b=hi)
  return (u32)f2bf(a) | ((u32)f2bf(b) << 16);
}

DEV s16x8 ld8(const u16* p) {
  uint4 u = *reinterpret_cast<const uint4*>(p);
  return __builtin_bit_cast(s16x8, u);
}

DEV f32x4 mfma16(s16x8 a, s16x8 b, f32x4 c) {
  return __builtin_amdgcn_mfma_f32_16x16x32_bf16(a, b, c, 0, 0, 0);
}

// async global->LDS, 16B per lane. LDS dest = uniform base + lane*16.
DEV void gld16(const void* g, void* l) {
  __builtin_amdgcn_global_load_lds(
      (const __attribute__((address_space(1))) void*)g,
      (__attribute__((address_space(3))) void*)l, 16, 0, 0);
}

// ---------- prep kernels ----------

__global__ void k_cvt_x(const float* __restrict__ x, u16* __restrict__ xb) {
  int i = blockIdx.x * blockDim.x + threadIdx.x;
  float4 v = reinterpret_cast<const float4*>(x)[i];
  u16 r0 = f2bf(v.x), r1 = f2bf(v.y), r2 = f2bf(v.z), r3 = f2bf(v.w);
  u32 lo = (u32)r0 | ((u32)r1 << 16);
  u32 hi = (u32)r2 | ((u32)r3 << 16);
  reinterpret_cast<uint2*>(xb)[i] = make_uint2(lo, hi);
}

// Build wT[R][c], R = s*2560 + h*320 + n  (s: 0=q,1=k,2=v), value = w[c][col(R)]
__global__ void k_tr_w(const float* __restrict__ wq, const float* __restrict__ wkv,
                       u16* __restrict__ wT) {
  int R0 = blockIdx.x * 32;
  int C0 = blockIdx.y * 32;
  int s = R0 / 2560, rem = R0 % 2560;
  int h = rem / 320, n0 = rem % 320;
  const float* src; int ld; int col0;
  if (s == 0) { src = wq;  ld = 2560; col0 = h * 320 + n0; }
  else        { src = wkv; ld = 5120; col0 = (s - 1) * 2560 + h * 320 + n0; }
  __shared__ float tile[32][33];
  int tx = threadIdx.x, ty = threadIdx.y;
  #pragma unroll
  for (int i = 0; i < 4; i++) {
    int c = C0 + ty + 8 * i;
    tile[ty + 8 * i][tx] = src[(size_t)c * ld + col0 + tx];
  }
  __syncthreads();
  #pragma unroll
  for (int i = 0; i < 4; i++) {
    int n = ty + 8 * i;
    wT[(size_t)(R0 + n) * 1024 + C0 + tx] = f2bf(tile[tx][n]);
  }
}

// woT[f][h*64+d] = w_o_w[h][f][d]
__global__ void k_tr_wo(const float* __restrict__ wow, u16* __restrict__ woT) {
  int f = blockIdx.x, d = threadIdx.x;
  #pragma unroll
  for (int h = 0; h < 8; h++)
    woT[(size_t)f * 512 + h * 64 + d] = f2bf(wow[((size_t)h * 1024 + f) * 64 + d]);
}

__global__ void k_bias(const float* __restrict__ wob, float* __restrict__ biasum) {
  int f = blockIdx.x * 256 + threadIdx.x;
  float s = 0.f;
  #pragma unroll
  for (int h = 0; h < 8; h++) s += wob[h * 1024 + f];
  biasum[f] = s;
}

// wsdT[j][c] : j<40 -> w_s col j ; j>=40 -> w_d col j-40
__global__ void k_tr_wsd(const float* __restrict__ ws, const float* __restrict__ wd,
                         float* __restrict__ wsdT) {
  int j = blockIdx.x;
  const float* src = (j < 40) ? ws : wd;
  int c = (j < 40) ? j : j - 40;
  for (int i = threadIdx.x; i < 1024; i += 256)
    wsdT[(size_t)j * 1024 + i] = src[(size_t)i * 40 + c];
}

// ---------- scores + topk (all fp32) ----------
__launch_bounds__(320)
__global__ void k_scores(const float* __restrict__ x, const float* __restrict__ wsdT,
                         int* __restrict__ eps_s, int* __restrict__ eps_d,
                         float* __restrict__ ss3, float* __restrict__ sd3) {
  int tokb = blockIdx.x * 8;
  __shared__ float xl[8][1028];
  __shared__ float sc[8][80];
  const float4* xsrc = reinterpret_cast<const float4*>(x + (size_t)tokb * 1024);
  for (int i = threadIdx.x; i < 2048; i += 320) {
    int tok = i >> 8, col4 = i & 255;
    *reinterpret_cast<float4*>(&xl[tok][col4 * 4]) = xsrc[i];
  }
  __syncthreads();
  {
    int tok = threadIdx.x & 7, j = threadIdx.x >> 3;
    const float4* wsp = reinterpret_cast<const float4*>(wsdT + (size_t)j * 1024);
    const float4* wdp = reinterpret_cast<const float4*>(wsdT + (size_t)(j + 40) * 1024);
    float as0 = 0.f, as1 = 0.f, ad0 = 0.f, ad1 = 0.f;
    #pragma unroll 4
    for (int k4 = 0; k4 < 256; k4 += 2) {
      float4 x0 = *reinterpret_cast<const float4*>(&xl[tok][k4 * 4]);
      float4 x1 = *reinterpret_cast<const float4*>(&xl[tok][k4 * 4 + 4]);
      float4 wsv0 = wsp[k4], wsv1 = wsp[k4 + 1];
      float4 wdv0 = wdp[k4], wdv1 = wdp[k4 + 1];
      as0 += x0.x * wsv0.x + x0.y * wsv0.y + x0.z * wsv0.z + x0.w * wsv0.w;
      as1 += x1.x * wsv1.x + x1.y * wsv1.y + x1.z * wsv1.z + x1.w * wsv1.w;
      ad0 += x0.x * wdv0.x + x0.y * wdv0.y + x0.z * wdv0.z + x0.w * wdv0.w;
      ad1 += x1.x * wdv1.x + x1.y * wdv1.y + x1.z * wdv1.z + x1.w * wdv1.w;
    }
    float as = as0 + as1, ad = ad0 + ad1;
    sc[tok][j]      = 1.f / (1.f + expf(-as));
    sc[tok][40 + j] = 1.f / (1.f + expf(-ad));
  }
  __syncthreads();
  int t2 = threadIdx.x;
  if (t2 < 128) {
    int tt = t2 >> 4, u = t2 & 15, h = u >> 1, which = u & 1;
    const float* S = &sc[tt][which * 40 + h * 5];
    float v[5];
    #pragma unroll
    for (int e = 0; e < 5; e++) v[e] = S[e];
    int tok = tokb + tt;
    int base = (tok * 8 + h) * 3;
    int* eps = which ? eps_d : eps_s;
    float* w3 = which ? sd3 : ss3;
    bool used[5] = {false, false, false, false, false};
    #pragma unroll
    for (int kk = 0; kk < 3; kk++) {
      float best = -1e30f; int bi = 0;
      #pragma unroll
      for (int e = 0; e < 5; e++)
        if (!used[e] && v[e] > best) { best = v[e]; bi = e; }
      used[bi] = true;
      eps[base + kk] = bi;
    }
    #pragma unroll
    for (int kk = 0; kk < 3; kk++) w3[base + kk] = S[kk]; // FIRST-K raw scores
  }
}

// ---------- fused projection + expert-select ----------
__launch_bounds__(512)
__global__ void k_proj(const u16* __restrict__ xb, const u16* __restrict__ wT,
                       const int* __restrict__ eps_d, const int* __restrict__ eps_s,
                       const float* __restrict__ sd3, const float* __restrict__ ss3,
                       u16* __restrict__ qw, u16* __restrict__ kw, u16* __restrict__ vw) {
  int tok0 = blockIdx.x * 128;
  int h = blockIdx.y;
  int s = blockIdx.z;
  int Rbase = (s * 8 + h) * 320;
  __shared__ alignas(16) u16 bsA[128 * 64];
  __shared__ alignas(16) u16 bsB[320 * 64];
  int wv = threadIdx.x >> 6, l = threadIdx.x & 63;
  int g = l >> 4, c = l & 15;
  f32x4 acc[20];
  #pragma unroll
  for (int i = 0; i < 20; i++) acc[i] = (f32x4){0.f, 0.f, 0.f, 0.f};

  const u16* wTp0 = wT + (size_t)Rbase * 1024;
  const u16* xbp0 = xb + (size_t)tok0 * 1024;

  for (int k0 = 0; k0 < 1024; k0 += 64) {
    __syncthreads();
    const u16* wTp = wTp0 + k0;
    #pragma unroll
    for (int j = 0; j < 5; j++) {
      int ch = wv * 320 + j * 64 + l;
      int row = ch >> 3, part = ch & 7;
      gld16(wTp + (size_t)row * 1024 + ((part * 8) ^ ((row & 7) * 8)),
            &bsB[(wv * 320 + j * 64) * 8]);
    }
    const u16* xbp = xbp0 + k0;
    #pragma unroll
    for (int j = 0; j < 2; j++) {
      int ch = wv * 128 + j * 64 + l;
      int row = ch >> 3, part = ch & 7;
      gld16(xbp + (size_t)row * 1024 + ((part * 8) ^ ((row & 7) * 8)),
            &bsA[(wv * 128 + j * 64) * 8]);
    }
    __syncthreads();

    #pragma unroll
    for (int kk = 0; kk < 2; kk++) {
      int off = (kk * 32 + g * 8) ^ ((c & 7) * 8);
      s16x8 a = *reinterpret_cast<const s16x8*>(&bsA[(wv * 16 + c) * 64 + off]);
      #pragma unroll
      for (int nt = 0; nt < 20; nt++) {
        s16x8 b = *reinterpret_cast<const s16x8*>(&bsB[(nt * 16 + c) * 64 + off]);
        acc[nt] = mfma16(a, b, acc[nt]);
      }
    }
  }

  const int* eps = (s == 0) ? eps_d : eps_s;
  const float* w3 = (s == 0) ? sd3 : ss3;
  float scale = (s == 0) ? 0.125f : 1.0f;
  u16* dst = (s == 0) ? qw : (s == 1 ? kw : vw);
  #pragma unroll
  for (int r = 0; r < 4; r++) {
    int tokr = tok0 + wv * 16 + g * 4 + r;
    int base = (tokr * 8 + h) * 3;
    int e0 = eps[base], e1 = eps[base + 1], e2 = eps[base + 2];
    float w0 = w3[base], w1 = w3[base + 1], w2 = w3[base + 2];
    float we[5];
    #pragma unroll
    for (int e = 0; e < 5; e++)
      we[e] = (e0 == e ? w0 : 0.f) + (e1 == e ? w1 : 0.f) + (e2 == e ? w2 : 0.f);
    int b = tokr >> 11, t = tokr & 2047;
    size_t obase = (((size_t)b * 8 + h) * 2048 + t) * 64;
    #pragma unroll
    for (int dh = 0; dh < 4; dh++) {
      float vq = 0.f;
      #pragma unroll
      for (int e = 0; e < 5; e++) vq += we[e] * acc[e * 4 + dh][r];
      dst[obase + dh * 16 + c] = f2bf(vq * scale);
    }
  }
}

// (B,H,T,D) -> (B,H,D,T)
__global__ void k_trv(const u16* __restrict__ vw, u16* __restrict__ vT) {
  int bh = blockIdx.z;
  int t0 = blockIdx.x * 32, d0 = blockIdx.y * 32;
  __shared__ u16 tile[32][33];
  const u16* src = vw + (size_t)bh * 2048 * 64;
  u16* dst = vT + (size_t)bh * 64 * 2048;
  int tx = threadIdx.x, ty = threadIdx.y;
  #pragma unroll
  for (int i = 0; i < 4; i++)
    tile[ty + 8 * i][tx] = src[(size_t)(t0 + ty + 8 * i) * 64 + d0 + tx];
  __syncthreads();
  #pragma unroll
  for (int i = 0; i < 4; i++)
    dst[(size_t)(d0 + ty + 8 * i) * 2048 + t0 + tx] = tile[tx][ty + 8 * i];
}

// ---------- flash attention: swapped QK^T -> lane-local P -> K=32 PV ----------
// 8 waves: wave = (seg, wq). seg scans keys [seg*1024, +1024) for q-rows
// [q0+wq*16, +16). Swapped QK (A=K, B=Q) gives S^T: lane (g,c) holds
// S[key=kb+4g+r][q=c] in s0[r] and S[key=kb+16+4g+r][q=c] in s1[r]
// (HW-verified C/D layout). PV uses the verified K=32 MFMA with a
// consistent positional key map mu(g,j) = (j<4 ? kb+4g+j : kb+16+4g+(j-4))
// on BOTH operands (contraction is positional). No LDS in the loop.
__launch_bounds__(512)
__global__ void k_attn(const u16* __restrict__ qw, const u16* __restrict__ kw,
                       const u16* __restrict__ vT, u16* __restrict__ ow) {
  int bh = blockIdx.y;
  int b = bh >> 3, h = bh & 7;
  int q0 = blockIdx.x * 64;
  int wv = threadIdx.x >> 6, l = threadIdx.x & 63;
  int seg = wv >> 2, wq = wv & 3;
  int g = l >> 4, c = l & 15;
  const u16* qp = qw + (size_t)bh * 2048 * 64;
  const u16* kp = kw + (size_t)bh * 2048 * 64;
  const u16* vp = vT + (size_t)bh * 64 * 2048;
  __shared__ float os[4][16][64];    // seg1 partial O
  __shared__ float ssl[2][4][16];    // per-seg, per-wq, per-q denom

  // Q fragment (B-operand): lane (g,c) holds Q[q=c][d=8g..8g+7]
  s16x8 qa0 = ld8(qp + (size_t)(q0 + wq * 16 + c) * 64 + 0 + 8 * g);
  s16x8 qa1 = ld8(qp + (size_t)(q0 + wq * 16 + c) * 64 + 32 + 8 * g);

  f32x4 o[4];
  #pragma unroll
  for (int i = 0; i < 4; i++) o[i] = (f32x4){0.f, 0.f, 0.f, 0.f};
  float ssum = 0.f;   // denom partial for q = c

  const int kb0 = seg * 1024;
  for (int kb = kb0; kb < kb0 + 1024; kb += 32) {
    // K fragments (A-operand): lane (g,c) holds K[kb+c(+16)][d=8g..+7]
    s16x8 ka0 = ld8(kp + (size_t)(kb + c) * 64 + 0 + 8 * g);
    s16x8 ka1 = ld8(kp + (size_t)(kb + c) * 64 + 32 + 8 * g);
    s16x8 kc0 = ld8(kp + (size_t)(kb + 16 + c) * 64 + 0 + 8 * g);
    s16x8 kc1 = ld8(kp + (size_t)(kb + 16 + c) * 64 + 32 + 8 * g);
    // V fragments (B-operand, positional map mu): positions 0..3 = keys
    // kb+4g..+3, positions 4..7 = keys kb+16+4g..+3, col c -> d=nt*16+c.
    uint4 vv[4];
    #pragma unroll
    for (int nt = 0; nt < 4; nt++) {
      const u16* vb = vp + (size_t)(nt * 16 + c) * 2048 + kb + 4 * g;
      uint2 lo = *reinterpret_cast<const uint2*>(vb);
      uint2 hi = *reinterpret_cast<const uint2*>(vb + 16);  // keys kb+16+4g..+3
      vv[nt] = make_uint4(lo.x, lo.y, hi.x, hi.y);
    }

    f32x4 s0 = (f32x4){0.f, 0.f, 0.f, 0.f};
    f32x4 s1 = (f32x4){0.f, 0.f, 0.f, 0.f};
    s0 = mfma16(ka0, qa0, s0);
    s0 = mfma16(ka1, qa1, s0);
    s1 = mfma16(kc0, qa0, s1);
    s1 = mfma16(kc1, qa1, s1);

    float p00 = __expf(s0[0]), p01 = __expf(s0[1]);
    float p02 = __expf(s0[2]), p03 = __expf(s0[3]);
    float p10 = __expf(s1[0]), p11 = __expf(s1[1]);
    float p12 = __expf(s1[2]), p13 = __expf(s1[3]);
    ssum += (p00 + p01) + (p02 + p03) + (p10 + p11) + (p12 + p13);

    // A-frag positions: [p(4g+0..3), p(16+4g+0..3)] -- matches vv's mu map.
    uint4 pw = make_uint4(pk2(p00, p01), pk2(p02, p03),
                          pk2(p10, p11), pk2(p12, p13));
    s16x8 pa = __builtin_bit_cast(s16x8, pw);

    #pragma unroll
    for (int nt = 0; nt < 4; nt++)
      o[nt] = mfma16(pa, __builtin_bit_cast(s16x8, vv[nt]), o[nt]);
  }

  // ssum is per-(g,c) partial over its key slots; reduce over g (bits 4,5).
  ssum += __shfl_xor(ssum, 16, 64);
  ssum += __shfl_xor(ssum, 32, 64);
  if (g == 0) ssl[seg][wq][c] = ssum;   // lanes 0..15: q=c

  if (seg == 1) {
    #pragma unroll
    for (int r = 0; r < 4; r++)
      #pragma unroll
      for (int nt = 0; nt < 4; nt++)
        os[wq][g * 4 + r][nt * 16 + c] = o[nt][r];
  }
  __syncthreads();
  if (seg == 0) {
    #pragma unroll
    for (int r = 0; r < 4; r++) {
      int q = g * 4 + r;
      float sm = ssl[0][wq][q] + ssl[1][wq][q];
      float inv = 1.f / sm;
      int t = q0 + wq * 16 + q;
      #pragma unroll
      for (int nt = 0; nt < 4; nt++) {
        float val = (o[nt][r] + os[wq][q][nt * 16 + c]) * inv;
        ow[((size_t)(b * 2048 + t)) * 512 + h * 64 + nt * 16 + c] = f2bf(val);
      }
    }
  }
}

// ---------- output projection ----------
__launch_bounds__(512)
__global__ void k_oproj(const u16* __restrict__ ow, const u16* __restrict__ woT,
                        const float* __restrict__ biasum, float* __restrict__ out) {
  int t0 = blockIdx.x * 128, f0 = blockIdx.y * 64;
  int wv = threadIdx.x >> 6, l = threadIdx.x & 63;
  int g = l >> 4, c = l & 15;
  f32x4 acc[4];
  #pragma unroll
  for (int i = 0; i < 4; i++) acc[i] = (f32x4){0.f, 0.f, 0.f, 0.f};
  for (int k0 = 0; k0 < 512; k0 += 32) {
    s16x8 a = ld8(ow + (size_t)(t0 + wv * 16 + c) * 512 + k0 + 8 * g);
    #pragma unroll
    for (int nt = 0; nt < 4; nt++) {
      s16x8 bfr = ld8(woT + (size_t)(f0 + nt * 16 + c) * 512 + k0 + 8 * g);
      acc[nt] = mfma16(a, bfr, acc[nt]);
    }
  }
  #pragma unroll
  for (int r = 0; r < 4; r++) {
    int t = t0 + wv * 16 + g * 4 + r;
    #pragma unroll
    for (int nt = 0; nt < 4; nt++) {
      int f = f0 + nt * 16 + c;
      out[(size_t)t * 1024 + f] = acc[nt][r] + biasum[f];
    }
  }
}

extern "C" void kernel_launch(void* const* d_in, const int* in_sizes, int n_in,
                              void* d_out, int out_size, void* d_ws, size_t ws_size,
                              hipStream_t stream) {
  const float* x    = (const float*)d_in[0];
  const float* w_q  = (const float*)d_in[1];
  const float* w_kv = (const float*)d_in[2];
  const float* w_s  = (const float*)d_in[3];
  const float* w_d  = (const float*)d_in[4];
  const float* w_ow = (const float*)d_in[5];
  const float* w_ob = (const float*)d_in[6];
  float* out = (float*)d_out;

  char* ws = (char*)d_ws;
  size_t o = 0;
  u16* xb     = (u16*)(ws + o); o += (size_t)NTOK * DIMc * 2;
  u16* wT     = (u16*)(ws + o); o += (size_t)3 * NQ * DIMc * 2;
  u16* woT    = (u16*)(ws + o); o += (size_t)1024 * 512 * 2;
  float* bsum = (float*)(ws + o); o += 4096;
  float* wsdT = (float*)(ws + o); o += (size_t)80 * 1024 * 4;
  int* eps_s  = (int*)(ws + o); o += (size_t)NTOK * 8 * 3 * 4;
  int* eps_d  = (int*)(ws + o); o += (size_t)NTOK * 8 * 3 * 4;
  float* ss3  = (float*)(ws + o); o += (size_t)NTOK * 8 * 3 * 4;
  float* sd3  = (float*)(ws + o); o += (size_t)NTOK * 8 * 3 * 4;
  u16* qw     = (u16*)(ws + o); o += (size_t)NTOK * 512 * 2;
  u16* kw     = (u16*)(ws + o); o += (size_t)NTOK * 512 * 2;
  u16* vw     = (u16*)(ws + o); o += (size_t)NTOK * 512 * 2;
  u16* vTw    = (u16*)(ws + o); o += (size_t)NTOK * 512 * 2;
  u16* oww    = (u16*)(ws + o); o += (size_t)NTOK * 512 * 2;

  k_cvt_x<<<4096, 256, 0, stream>>>(x, xb);
  k_tr_w<<<dim3(240, 32), dim3(32, 8), 0, stream>>>(w_q, w_kv, wT);
  k_tr_wo<<<1024, 64, 0, stream>>>(w_ow, woT);
  k_bias<<<4, 256, 0, stream>>>(w_ob, bsum);
  k_tr_wsd<<<80, 256, 0, stream>>>(w_s, w_d, wsdT);
  k_scores<<<512, 320, 0, stream>>>(x, wsdT, eps_s, eps_d, ss3, sd3);
  k_proj<<<dim3(32, 8, 3), 512, 0, stream>>>(xb, wT, eps_d, eps_s, sd3, ss3, qw, kw, vw);
  k_trv<<<dim3(64, 2, 16), dim3(32, 8), 0, stream>>>(vw, vTw);
  k_attn<<<dim3(32, 16), 512, 0, stream>>>(qw, kw, vTw, oww);
  k_oproj<<<dim3(32, 16), 512, 0, stream>>>(oww, woT, bsum, out);
}

// Round 8
// 301.966 us; speedup vs baseline: 1.1762x; 1.1762x over previous
//
#include <hip/hip_runtime.h>

#define DEV __device__ __forceinline__

typedef float f32x4 __attribute__((ext_vector_type(4)));
typedef short s16x8 __attribute__((ext_vector_type(8)));
typedef unsigned short u16;
typedef unsigned int u32;

constexpr int Bb = 2, Tt = 2048, DIMc = 1024, Hh = 8, Ee = 5, Dd = 64;
constexpr int NTOK = Bb * Tt;   // 4096
constexpr int NQ = Hh * Ee * Dd; // 2560

DEV u16 f2bf(float f) {
  union { float f; u32 u; } v; v.f = f;
  u32 r = v.u + 0x7fffu + ((v.u >> 16) & 1u);
  return (u16)(r >> 16);
}

DEV u32 pk2(float a, float b) {  // two f32 -> packed bf16 pair (a=lo, b=hi)
  return (u32)f2bf(a) | ((u32)f2bf(b) << 16);
}

DEV s16x8 ld8(const u16* p) {
  uint4 u = *reinterpret_cast<const uint4*>(p);
  return __builtin_bit_cast(s16x8, u);
}

DEV f32x4 mfma16(s16x8 a, s16x8 b, f32x4 c) {
  return __builtin_amdgcn_mfma_f32_16x16x32_bf16(a, b, c, 0, 0, 0);
}

// async global->LDS, 16B per lane. LDS dest = uniform base + lane*16.
DEV void gld16(const void* g, void* l) {
  __builtin_amdgcn_global_load_lds(
      (const __attribute__((address_space(1))) void*)g,
      (__attribute__((address_space(3))) void*)l, 16, 0, 0);
}

// ---------- prep kernels ----------

__global__ void k_cvt_x(const float* __restrict__ x, u16* __restrict__ xb) {
  int i = blockIdx.x * blockDim.x + threadIdx.x;
  float4 v = reinterpret_cast<const float4*>(x)[i];
  u16 r0 = f2bf(v.x), r1 = f2bf(v.y), r2 = f2bf(v.z), r3 = f2bf(v.w);
  u32 lo = (u32)r0 | ((u32)r1 << 16);
  u32 hi = (u32)r2 | ((u32)r3 << 16);
  reinterpret_cast<uint2*>(xb)[i] = make_uint2(lo, hi);
}

// Build wT[R][c], R = s*2560 + h*320 + n  (s: 0=q,1=k,2=v), value = w[c][col(R)]
__global__ void k_tr_w(const float* __restrict__ wq, const float* __restrict__ wkv,
                       u16* __restrict__ wT) {
  int R0 = blockIdx.x * 32;
  int C0 = blockIdx.y * 32;
  int s = R0 / 2560, rem = R0 % 2560;
  int h = rem / 320, n0 = rem % 320;
  const float* src; int ld; int col0;
  if (s == 0) { src = wq;  ld = 2560; col0 = h * 320 + n0; }
  else        { src = wkv; ld = 5120; col0 = (s - 1) * 2560 + h * 320 + n0; }
  __shared__ float tile[32][33];
  int tx = threadIdx.x, ty = threadIdx.y;
  #pragma unroll
  for (int i = 0; i < 4; i++) {
    int c = C0 + ty + 8 * i;
    tile[ty + 8 * i][tx] = src[(size_t)c * ld + col0 + tx];
  }
  __syncthreads();
  #pragma unroll
  for (int i = 0; i < 4; i++) {
    int n = ty + 8 * i;
    wT[(size_t)(R0 + n) * 1024 + C0 + tx] = f2bf(tile[tx][n]);
  }
}

// woT[f][h*64+d] = w_o_w[h][f][d]
__global__ void k_tr_wo(const float* __restrict__ wow, u16* __restrict__ woT) {
  int f = blockIdx.x, d = threadIdx.x;
  #pragma unroll
  for (int h = 0; h < 8; h++)
    woT[(size_t)f * 512 + h * 64 + d] = f2bf(wow[((size_t)h * 1024 + f) * 64 + d]);
}

__global__ void k_bias(const float* __restrict__ wob, float* __restrict__ biasum) {
  int f = blockIdx.x * 256 + threadIdx.x;
  float s = 0.f;
  #pragma unroll
  for (int h = 0; h < 8; h++) s += wob[h * 1024 + f];
  biasum[f] = s;
}

// wsdT[j][c] : j<40 -> w_s col j ; j>=40 -> w_d col j-40
__global__ void k_tr_wsd(const float* __restrict__ ws, const float* __restrict__ wd,
                         float* __restrict__ wsdT) {
  int j = blockIdx.x;
  const float* src = (j < 40) ? ws : wd;
  int c = (j < 40) ? j : j - 40;
  for (int i = threadIdx.x; i < 1024; i += 256)
    wsdT[(size_t)j * 1024 + i] = src[(size_t)i * 40 + c];
}

// ---------- scores + topk (all fp32) ----------
__launch_bounds__(320)
__global__ void k_scores(const float* __restrict__ x, const float* __restrict__ wsdT,
                         int* __restrict__ eps_s, int* __restrict__ eps_d,
                         float* __restrict__ ss3, float* __restrict__ sd3) {
  int tokb = blockIdx.x * 8;
  __shared__ float xl[8][1028];
  __shared__ float sc[8][80];
  const float4* xsrc = reinterpret_cast<const float4*>(x + (size_t)tokb * 1024);
  for (int i = threadIdx.x; i < 2048; i += 320) {
    int tok = i >> 8, col4 = i & 255;
    *reinterpret_cast<float4*>(&xl[tok][col4 * 4]) = xsrc[i];
  }
  __syncthreads();
  {
    int tok = threadIdx.x & 7, j = threadIdx.x >> 3;
    const float4* wsp = reinterpret_cast<const float4*>(wsdT + (size_t)j * 1024);
    const float4* wdp = reinterpret_cast<const float4*>(wsdT + (size_t)(j + 40) * 1024);
    float as0 = 0.f, as1 = 0.f, ad0 = 0.f, ad1 = 0.f;
    #pragma unroll 4
    for (int k4 = 0; k4 < 256; k4 += 2) {
      float4 x0 = *reinterpret_cast<const float4*>(&xl[tok][k4 * 4]);
      float4 x1 = *reinterpret_cast<const float4*>(&xl[tok][k4 * 4 + 4]);
      float4 wsv0 = wsp[k4], wsv1 = wsp[k4 + 1];
      float4 wdv0 = wdp[k4], wdv1 = wdp[k4 + 1];
      as0 += x0.x * wsv0.x + x0.y * wsv0.y + x0.z * wsv0.z + x0.w * wsv0.w;
      as1 += x1.x * wsv1.x + x1.y * wsv1.y + x1.z * wsv1.z + x1.w * wsv1.w;
      ad0 += x0.x * wdv0.x + x0.y * wdv0.y + x0.z * wdv0.z + x0.w * wdv0.w;
      ad1 += x1.x * wdv1.x + x1.y * wdv1.y + x1.z * wdv1.z + x1.w * wdv1.w;
    }
    float as = as0 + as1, ad = ad0 + ad1;
    sc[tok][j]      = 1.f / (1.f + expf(-as));
    sc[tok][40 + j] = 1.f / (1.f + expf(-ad));
  }
  __syncthreads();
  int t2 = threadIdx.x;
  if (t2 < 128) {
    int tt = t2 >> 4, u = t2 & 15, h = u >> 1, which = u & 1;
    const float* S = &sc[tt][which * 40 + h * 5];
    float v[5];
    #pragma unroll
    for (int e = 0; e < 5; e++) v[e] = S[e];
    int tok = tokb + tt;
    int base = (tok * 8 + h) * 3;
    int* eps = which ? eps_d : eps_s;
    float* w3 = which ? sd3 : ss3;
    bool used[5] = {false, false, false, false, false};
    #pragma unroll
    for (int kk = 0; kk < 3; kk++) {
      float best = -1e30f; int bi = 0;
      #pragma unroll
      for (int e = 0; e < 5; e++)
        if (!used[e] && v[e] > best) { best = v[e]; bi = e; }
      used[bi] = true;
      eps[base + kk] = bi;
    }
    #pragma unroll
    for (int kk = 0; kk < 3; kk++) w3[base + kk] = S[kk]; // FIRST-K raw scores
  }
}

// ---------- fused projection + expert-select ----------
__launch_bounds__(512)
__global__ void k_proj(const u16* __restrict__ xb, const u16* __restrict__ wT,
                       const int* __restrict__ eps_d, const int* __restrict__ eps_s,
                       const float* __restrict__ sd3, const float* __restrict__ ss3,
                       u16* __restrict__ qw, u16* __restrict__ kw, u16* __restrict__ vw) {
  int tok0 = blockIdx.x * 128;
  int h = blockIdx.y;
  int s = blockIdx.z;
  int Rbase = (s * 8 + h) * 320;
  __shared__ alignas(16) u16 bsA[128 * 64];
  __shared__ alignas(16) u16 bsB[320 * 64];
  int wv = threadIdx.x >> 6, l = threadIdx.x & 63;
  int g = l >> 4, c = l & 15;
  f32x4 acc[20];
  #pragma unroll
  for (int i = 0; i < 20; i++) acc[i] = (f32x4){0.f, 0.f, 0.f, 0.f};

  const u16* wTp0 = wT + (size_t)Rbase * 1024;
  const u16* xbp0 = xb + (size_t)tok0 * 1024;

  for (int k0 = 0; k0 < 1024; k0 += 64) {
    __syncthreads();
    const u16* wTp = wTp0 + k0;
    #pragma unroll
    for (int j = 0; j < 5; j++) {
      int ch = wv * 320 + j * 64 + l;
      int row = ch >> 3, part = ch & 7;
      gld16(wTp + (size_t)row * 1024 + ((part * 8) ^ ((row & 7) * 8)),
            &bsB[(wv * 320 + j * 64) * 8]);
    }
    const u16* xbp = xbp0 + k0;
    #pragma unroll
    for (int j = 0; j < 2; j++) {
      int ch = wv * 128 + j * 64 + l;
      int row = ch >> 3, part = ch & 7;
      gld16(xbp + (size_t)row * 1024 + ((part * 8) ^ ((row & 7) * 8)),
            &bsA[(wv * 128 + j * 64) * 8]);
    }
    __syncthreads();

    #pragma unroll
    for (int kk = 0; kk < 2; kk++) {
      int off = (kk * 32 + g * 8) ^ ((c & 7) * 8);
      s16x8 a = *reinterpret_cast<const s16x8*>(&bsA[(wv * 16 + c) * 64 + off]);
      #pragma unroll
      for (int nt = 0; nt < 20; nt++) {
        s16x8 b = *reinterpret_cast<const s16x8*>(&bsB[(nt * 16 + c) * 64 + off]);
        acc[nt] = mfma16(a, b, acc[nt]);
      }
    }
  }

  const int* eps = (s == 0) ? eps_d : eps_s;
  const float* w3 = (s == 0) ? sd3 : ss3;
  float scale = (s == 0) ? 0.125f : 1.0f;
  u16* dst = (s == 0) ? qw : (s == 1 ? kw : vw);
  #pragma unroll
  for (int r = 0; r < 4; r++) {
    int tokr = tok0 + wv * 16 + g * 4 + r;
    int base = (tokr * 8 + h) * 3;
    int e0 = eps[base], e1 = eps[base + 1], e2 = eps[base + 2];
    float w0 = w3[base], w1 = w3[base + 1], w2 = w3[base + 2];
    float we[5];
    #pragma unroll
    for (int e = 0; e < 5; e++)
      we[e] = (e0 == e ? w0 : 0.f) + (e1 == e ? w1 : 0.f) + (e2 == e ? w2 : 0.f);
    int b = tokr >> 11, t = tokr & 2047;
    size_t obase = (((size_t)b * 8 + h) * 2048 + t) * 64;
    #pragma unroll
    for (int dh = 0; dh < 4; dh++) {
      float vq = 0.f;
      #pragma unroll
      for (int e = 0; e < 5; e++) vq += we[e] * acc[e * 4 + dh][r];
      dst[obase + dh * 16 + c] = f2bf(vq * scale);
    }
  }
}

// (B,H,T,D) -> (B,H,D,T') with T' mu-permuted inside each 32-key tile:
// storage position p(k) = 8*((k&15)>>2) + (k&3) + (k>=16 ? 4 : 0).
// A 16B read at tile+8g then holds keys {4g..4g+3, 16+4g..16+4g+3} -- the
// exact B-fragment positional map used by k_attn's PV MFMA.
__global__ void k_trv(const u16* __restrict__ vw, u16* __restrict__ vT) {
  int bh = blockIdx.z;
  int t0 = blockIdx.x * 32, d0 = blockIdx.y * 32;
  __shared__ u16 tile[32][33];
  const u16* src = vw + (size_t)bh * 2048 * 64;
  u16* dst = vT + (size_t)bh * 64 * 2048;
  int tx = threadIdx.x, ty = threadIdx.y;
  #pragma unroll
  for (int i = 0; i < 4; i++)
    tile[ty + 8 * i][tx] = src[(size_t)(t0 + ty + 8 * i) * 64 + d0 + tx];
  __syncthreads();
  int p = 8 * ((tx & 15) >> 2) + (tx & 3) + ((tx >= 16) ? 4 : 0);
  #pragma unroll
  for (int i = 0; i < 4; i++)
    dst[(size_t)(d0 + ty + 8 * i) * 2048 + t0 + p] = tile[tx][ty + 8 * i];
}

// ---------- flash attention: swapped QK^T -> lane-local P -> K=32 PV ----------
// 8 waves: wave = (seg, wq); seg scans keys [seg*1024,+1024) for 16 q-rows.
// Swapped QK (A=K, B=Q) gives S^T lane-locally; PV contracts the packed P
// A-fragment against mu-permuted vT B-fragments (single ld8 each).
// Explicit 2-deep register prefetch (named A/B sets), no LDS in the loop.
__launch_bounds__(512)
__global__ void k_attn(const u16* __restrict__ qw, const u16* __restrict__ kw,
                       const u16* __restrict__ vT, u16* __restrict__ ow) {
  int bh = blockIdx.y;
  int b = bh >> 3, h = bh & 7;
  int q0 = blockIdx.x * 64;
  int wv = threadIdx.x >> 6, l = threadIdx.x & 63;
  int seg = wv >> 2, wq = wv & 3;
  int g = l >> 4, c = l & 15;
  const u16* qp = qw + (size_t)bh * 2048 * 64;
  const u16* kp = kw + (size_t)bh * 2048 * 64;
  const u16* vp = vT + (size_t)bh * 64 * 2048;
  __shared__ float os[4][16][64];    // seg1 partial O
  __shared__ float ssl[2][4][16];    // per-seg, per-wq, per-q denom

  s16x8 qa0 = ld8(qp + (size_t)(q0 + wq * 16 + c) * 64 + 0 + 8 * g);
  s16x8 qa1 = ld8(qp + (size_t)(q0 + wq * 16 + c) * 64 + 32 + 8 * g);

  f32x4 o[4];
  #pragma unroll
  for (int i = 0; i < 4; i++) o[i] = (f32x4){0.f, 0.f, 0.f, 0.f};
  float ssum = 0.f;   // denom partial for q = c

  const int kb0 = seg * 1024;

  s16x8 kA0, kA1, kA2, kA3, vA0, vA1, vA2, vA3;
  s16x8 kB0, kB1, kB2, kB3, vB0, vB1, vB2, vB3;

#define LOAD_SET(K0,K1,K2,K3,V0,V1,V2,V3,KB)                                \
  K0 = ld8(kp + (size_t)((KB) + c) * 64 + 0 + 8 * g);                       \
  K1 = ld8(kp + (size_t)((KB) + c) * 64 + 32 + 8 * g);                      \
  K2 = ld8(kp + (size_t)((KB) + 16 + c) * 64 + 0 + 8 * g);                  \
  K3 = ld8(kp + (size_t)((KB) + 16 + c) * 64 + 32 + 8 * g);                 \
  V0 = ld8(vp + (size_t)(0 * 16 + c) * 2048 + (KB) + 8 * g);                \
  V1 = ld8(vp + (size_t)(1 * 16 + c) * 2048 + (KB) + 8 * g);                \
  V2 = ld8(vp + (size_t)(2 * 16 + c) * 2048 + (KB) + 8 * g);                \
  V3 = ld8(vp + (size_t)(3 * 16 + c) * 2048 + (KB) + 8 * g);

#define COMPUTE_SET(K0,K1,K2,K3,V0,V1,V2,V3)                                \
  {                                                                         \
    f32x4 s0 = (f32x4){0.f, 0.f, 0.f, 0.f};                                 \
    f32x4 s1 = (f32x4){0.f, 0.f, 0.f, 0.f};                                 \
    s0 = mfma16(K0, qa0, s0);                                               \
    s0 = mfma16(K1, qa1, s0);                                               \
    s1 = mfma16(K2, qa0, s1);                                               \
    s1 = mfma16(K3, qa1, s1);                                               \
    float p00 = __expf(s0[0]), p01 = __expf(s0[1]);                         \
    float p02 = __expf(s0[2]), p03 = __expf(s0[3]);                         \
    float p10 = __expf(s1[0]), p11 = __expf(s1[1]);                         \
    float p12 = __expf(s1[2]), p13 = __expf(s1[3]);                         \
    ssum += (p00 + p01) + (p02 + p03) + (p10 + p11) + (p12 + p13);          \
    uint4 pw = make_uint4(pk2(p00, p01), pk2(p02, p03),                     \
                          pk2(p10, p11), pk2(p12, p13));                    \
    s16x8 pa = __builtin_bit_cast(s16x8, pw);                               \
    o[0] = mfma16(pa, V0, o[0]);                                            \
    o[1] = mfma16(pa, V1, o[1]);                                            \
    o[2] = mfma16(pa, V2, o[2]);                                            \
    o[3] = mfma16(pa, V3, o[3]);                                            \
  }

  LOAD_SET(kA0, kA1, kA2, kA3, vA0, vA1, vA2, vA3, kb0)
  for (int it = 0; it < 16; it++) {
    int kb = kb0 + it * 64;
    LOAD_SET(kB0, kB1, kB2, kB3, vB0, vB1, vB2, vB3, kb + 32)
    COMPUTE_SET(kA0, kA1, kA2, kA3, vA0, vA1, vA2, vA3)
    LOAD_SET(kA0, kA1, kA2, kA3, vA0, vA1, vA2, vA3, kb + 64)
    COMPUTE_SET(kB0, kB1, kB2, kB3, vB0, vB1, vB2, vB3)
  }
#undef LOAD_SET
#undef COMPUTE_SET

  // ssum is per-(g,c) partial over its key slots; reduce over g (bits 4,5).
  ssum += __shfl_xor(ssum, 16, 64);
  ssum += __shfl_xor(ssum, 32, 64);
  if (g == 0) ssl[seg][wq][c] = ssum;   // lanes 0..15: q=c

  if (seg == 1) {
    #pragma unroll
    for (int r = 0; r < 4; r++)
      #pragma unroll
      for (int nt = 0; nt < 4; nt++)
        os[wq][g * 4 + r][nt * 16 + c] = o[nt][r];
  }
  __syncthreads();
  if (seg == 0) {
    #pragma unroll
    for (int r = 0; r < 4; r++) {
      int q = g * 4 + r;
      float sm = ssl[0][wq][q] + ssl[1][wq][q];
      float inv = 1.f / sm;
      int t = q0 + wq * 16 + q;
      #pragma unroll
      for (int nt = 0; nt < 4; nt++) {
        float val = (o[nt][r] + os[wq][q][nt * 16 + c]) * inv;
        ow[((size_t)(b * 2048 + t)) * 512 + h * 64 + nt * 16 + c] = f2bf(val);
      }
    }
  }
}

// ---------- output projection ----------
__launch_bounds__(512)
__global__ void k_oproj(const u16* __restrict__ ow, const u16* __restrict__ woT,
                        const float* __restrict__ biasum, float* __restrict__ out) {
  int t0 = blockIdx.x * 128, f0 = blockIdx.y * 64;
  int wv = threadIdx.x >> 6, l = threadIdx.x & 63;
  int g = l >> 4, c = l & 15;
  f32x4 acc[4];
  #pragma unroll
  for (int i = 0; i < 4; i++) acc[i] = (f32x4){0.f, 0.f, 0.f, 0.f};
  for (int k0 = 0; k0 < 512; k0 += 32) {
    s16x8 a = ld8(ow + (size_t)(t0 + wv * 16 + c) * 512 + k0 + 8 * g);
    #pragma unroll
    for (int nt = 0; nt < 4; nt++) {
      s16x8 bfr = ld8(woT + (size_t)(f0 + nt * 16 + c) * 512 + k0 + 8 * g);
      acc[nt] = mfma16(a, bfr, acc[nt]);
    }
  }
  #pragma unroll
  for (int r = 0; r < 4; r++) {
    int t = t0 + wv * 16 + g * 4 + r;
    #pragma unroll
    for (int nt = 0; nt < 4; nt++) {
      int f = f0 + nt * 16 + c;
      out[(size_t)t * 1024 + f] = acc[nt][r] + biasum[f];
    }
  }
}

extern "C" void kernel_launch(void* const* d_in, const int* in_sizes, int n_in,
                              void* d_out, int out_size, void* d_ws, size_t ws_size,
                              hipStream_t stream) {
  const float* x    = (const float*)d_in[0];
  const float* w_q  = (const float*)d_in[1];
  const float* w_kv = (const float*)d_in[2];
  const float* w_s  = (const float*)d_in[3];
  const float* w_d  = (const float*)d_in[4];
  const float* w_ow = (const float*)d_in[5];
  const float* w_ob = (const float*)d_in[6];
  float* out = (float*)d_out;

  char* ws = (char*)d_ws;
  size_t o = 0;
  u16* xb     = (u16*)(ws + o); o += (size_t)NTOK * DIMc * 2;
  u16* wT     = (u16*)(ws + o); o += (size_t)3 * NQ * DIMc * 2;
  u16* woT    = (u16*)(ws + o); o += (size_t)1024 * 512 * 2;
  float* bsum = (float*)(ws + o); o += 4096;
  float* wsdT = (float*)(ws + o); o += (size_t)80 * 1024 * 4;
  int* eps_s  = (int*)(ws + o); o += (size_t)NTOK * 8 * 3 * 4;
  int* eps_d  = (int*)(ws + o); o += (size_t)NTOK * 8 * 3 * 4;
  float* ss3  = (float*)(ws + o); o += (size_t)NTOK * 8 * 3 * 4;
  float* sd3  = (float*)(ws + o); o += (size_t)NTOK * 8 * 3 * 4;
  u16* qw     = (u16*)(ws + o); o += (size_t)NTOK * 512 * 2;
  u16* kw     = (u16*)(ws + o); o += (size_t)NTOK * 512 * 2;
  u16* vw     = (u16*)(ws + o); o += (size_t)NTOK * 512 * 2;
  u16* vTw    = (u16*)(ws + o); o += (size_t)NTOK * 512 * 2;
  u16* oww    = (u16*)(ws + o); o += (size_t)NTOK * 512 * 2;

  k_cvt_x<<<4096, 256, 0, stream>>>(x, xb);
  k_tr_w<<<dim3(240, 32), dim3(32, 8), 0, stream>>>(w_q, w_kv, wT);
  k_tr_wo<<<1024, 64, 0, stream>>>(w_ow, woT);
  k_bias<<<4, 256, 0, stream>>>(w_ob, bsum);
  k_tr_wsd<<<80, 256, 0, stream>>>(w_s, w_d, wsdT);
  k_scores<<<512, 320, 0, stream>>>(x, wsdT, eps_s, eps_d, ss3, sd3);
  k_proj<<<dim3(32, 8, 3), 512, 0, stream>>>(xb, wT, eps_d, eps_s, sd3, ss3, qw, kw, vw);
  k_trv<<<dim3(64, 2, 16), dim3(32, 8), 0, stream>>>(vw, vTw);
  k_attn<<<dim3(32, 16), 512, 0, stream>>>(qw, kw, vTw, oww);
  k_oproj<<<dim3(32, 16), 512, 0, stream>>>(oww, woT, bsum, out);
}

// Round 9
// 225.338 us; speedup vs baseline: 1.5762x; 1.3401x over previous
//
#include <hip/hip_runtime.h>

#define DEV __device__ __forceinline__

typedef float f32x4 __attribute__((ext_vector_type(4)));
typedef short s16x8 __attribute__((ext_vector_type(8)));
typedef unsigned short u16;
typedef unsigned int u32;

constexpr int Bb = 2, Tt = 2048, DIMc = 1024, Hh = 8, Ee = 5, Dd = 64;
constexpr int NTOK = Bb * Tt;   // 4096
constexpr int NQ = Hh * Ee * Dd; // 2560

DEV u16 f2bf(float f) {
  union { float f; u32 u; } v; v.f = f;
  u32 r = v.u + 0x7fffu + ((v.u >> 16) & 1u);
  return (u16)(r >> 16);
}

DEV u32 pk2(float a, float b) {  // two f32 -> packed bf16 pair (a=lo, b=hi)
  return (u32)f2bf(a) | ((u32)f2bf(b) << 16);
}

DEV s16x8 ld8(const u16* p) {
  uint4 u = *reinterpret_cast<const uint4*>(p);
  return __builtin_bit_cast(s16x8, u);
}

DEV f32x4 mfma16(s16x8 a, s16x8 b, f32x4 c) {
  return __builtin_amdgcn_mfma_f32_16x16x32_bf16(a, b, c, 0, 0, 0);
}

// async global->LDS, 16B per lane. LDS dest = uniform base + lane*16.
DEV void gld16(const void* g, void* l) {
  __builtin_amdgcn_global_load_lds(
      (const __attribute__((address_space(1))) void*)g,
      (__attribute__((address_space(3))) void*)l, 16, 0, 0);
}

// ---------- prep kernels ----------

__global__ void k_cvt_x(const float* __restrict__ x, u16* __restrict__ xb) {
  int i = blockIdx.x * blockDim.x + threadIdx.x;
  float4 v = reinterpret_cast<const float4*>(x)[i];
  u16 r0 = f2bf(v.x), r1 = f2bf(v.y), r2 = f2bf(v.z), r3 = f2bf(v.w);
  u32 lo = (u32)r0 | ((u32)r1 << 16);
  u32 hi = (u32)r2 | ((u32)r3 << 16);
  reinterpret_cast<uint2*>(xb)[i] = make_uint2(lo, hi);
}

// Build wT[R][c], R = s*2560 + h*320 + n  (s: 0=q,1=k,2=v), value = w[c][col(R)]
__global__ void k_tr_w(const float* __restrict__ wq, const float* __restrict__ wkv,
                       u16* __restrict__ wT) {
  int R0 = blockIdx.x * 32;
  int C0 = blockIdx.y * 32;
  int s = R0 / 2560, rem = R0 % 2560;
  int h = rem / 320, n0 = rem % 320;
  const float* src; int ld; int col0;
  if (s == 0) { src = wq;  ld = 2560; col0 = h * 320 + n0; }
  else        { src = wkv; ld = 5120; col0 = (s - 1) * 2560 + h * 320 + n0; }
  __shared__ float tile[32][33];
  int tx = threadIdx.x, ty = threadIdx.y;
  #pragma unroll
  for (int i = 0; i < 4; i++) {
    int c = C0 + ty + 8 * i;
    tile[ty + 8 * i][tx] = src[(size_t)c * ld + col0 + tx];
  }
  __syncthreads();
  #pragma unroll
  for (int i = 0; i < 4; i++) {
    int n = ty + 8 * i;
    wT[(size_t)(R0 + n) * 1024 + C0 + tx] = f2bf(tile[tx][n]);
  }
}

// woT[f][h*64+d] = w_o_w[h][f][d]
__global__ void k_tr_wo(const float* __restrict__ wow, u16* __restrict__ woT) {
  int f = blockIdx.x, d = threadIdx.x;
  #pragma unroll
  for (int h = 0; h < 8; h++)
    woT[(size_t)f * 512 + h * 64 + d] = f2bf(wow[((size_t)h * 1024 + f) * 64 + d]);
}

__global__ void k_bias(const float* __restrict__ wob, float* __restrict__ biasum) {
  int f = blockIdx.x * 256 + threadIdx.x;
  float s = 0.f;
  #pragma unroll
  for (int h = 0; h < 8; h++) s += wob[h * 1024 + f];
  biasum[f] = s;
}

// wsdT[j][c] : j<40 -> w_s col j ; j>=40 -> w_d col j-40
__global__ void k_tr_wsd(const float* __restrict__ ws, const float* __restrict__ wd,
                         float* __restrict__ wsdT) {
  int j = blockIdx.x;
  const float* src = (j < 40) ? ws : wd;
  int c = (j < 40) ? j : j - 40;
  for (int i = threadIdx.x; i < 1024; i += 256)
    wsdT[(size_t)j * 1024 + i] = src[(size_t)i * 40 + c];
}

// ---------- scores + topk (all fp32) ----------
__launch_bounds__(320)
__global__ void k_scores(const float* __restrict__ x, const float* __restrict__ wsdT,
                         int* __restrict__ eps_s, int* __restrict__ eps_d,
                         float* __restrict__ ss3, float* __restrict__ sd3) {
  int tokb = blockIdx.x * 8;
  __shared__ float xl[8][1028];
  __shared__ float sc[8][80];
  const float4* xsrc = reinterpret_cast<const float4*>(x + (size_t)tokb * 1024);
  for (int i = threadIdx.x; i < 2048; i += 320) {
    int tok = i >> 8, col4 = i & 255;
    *reinterpret_cast<float4*>(&xl[tok][col4 * 4]) = xsrc[i];
  }
  __syncthreads();
  {
    int tok = threadIdx.x & 7, j = threadIdx.x >> 3;
    const float4* wsp = reinterpret_cast<const float4*>(wsdT + (size_t)j * 1024);
    const float4* wdp = reinterpret_cast<const float4*>(wsdT + (size_t)(j + 40) * 1024);
    float as0 = 0.f, as1 = 0.f, ad0 = 0.f, ad1 = 0.f;
    #pragma unroll 4
    for (int k4 = 0; k4 < 256; k4 += 2) {
      float4 x0 = *reinterpret_cast<const float4*>(&xl[tok][k4 * 4]);
      float4 x1 = *reinterpret_cast<const float4*>(&xl[tok][k4 * 4 + 4]);
      float4 wsv0 = wsp[k4], wsv1 = wsp[k4 + 1];
      float4 wdv0 = wdp[k4], wdv1 = wdp[k4 + 1];
      as0 += x0.x * wsv0.x + x0.y * wsv0.y + x0.z * wsv0.z + x0.w * wsv0.w;
      as1 += x1.x * wsv1.x + x1.y * wsv1.y + x1.z * wsv1.z + x1.w * wsv1.w;
      ad0 += x0.x * wdv0.x + x0.y * wdv0.y + x0.z * wdv0.z + x0.w * wdv0.w;
      ad1 += x1.x * wdv1.x + x1.y * wdv1.y + x1.z * wdv1.z + x1.w * wdv1.w;
    }
    float as = as0 + as1, ad = ad0 + ad1;
    sc[tok][j]      = 1.f / (1.f + expf(-as));
    sc[tok][40 + j] = 1.f / (1.f + expf(-ad));
  }
  __syncthreads();
  int t2 = threadIdx.x;
  if (t2 < 128) {
    int tt = t2 >> 4, u = t2 & 15, h = u >> 1, which = u & 1;
    const float* S = &sc[tt][which * 40 + h * 5];
    float v[5];
    #pragma unroll
    for (int e = 0; e < 5; e++) v[e] = S[e];
    int tok = tokb + tt;
    int base = (tok * 8 + h) * 3;
    int* eps = which ? eps_d : eps_s;
    float* w3 = which ? sd3 : ss3;
    bool used[5] = {false, false, false, false, false};
    #pragma unroll
    for (int kk = 0; kk < 3; kk++) {
      float best = -1e30f; int bi = 0;
      #pragma unroll
      for (int e = 0; e < 5; e++)
        if (!used[e] && v[e] > best) { best = v[e]; bi = e; }
      used[bi] = true;
      eps[base + kk] = bi;
    }
    #pragma unroll
    for (int kk = 0; kk < 3; kk++) w3[base + kk] = S[kk]; // FIRST-K raw scores
  }
}

// ---------- fused projection + expert-select ----------
__launch_bounds__(512)
__global__ void k_proj(const u16* __restrict__ xb, const u16* __restrict__ wT,
                       const int* __restrict__ eps_d, const int* __restrict__ eps_s,
                       const float* __restrict__ sd3, const float* __restrict__ ss3,
                       u16* __restrict__ qw, u16* __restrict__ kw, u16* __restrict__ vw) {
  int tok0 = blockIdx.x * 128;
  int h = blockIdx.y;
  int s = blockIdx.z;
  int Rbase = (s * 8 + h) * 320;
  __shared__ alignas(16) u16 bsA[128 * 64];
  __shared__ alignas(16) u16 bsB[320 * 64];
  int wv = threadIdx.x >> 6, l = threadIdx.x & 63;
  int g = l >> 4, c = l & 15;
  f32x4 acc[20];
  #pragma unroll
  for (int i = 0; i < 20; i++) acc[i] = (f32x4){0.f, 0.f, 0.f, 0.f};

  const u16* wTp0 = wT + (size_t)Rbase * 1024;
  const u16* xbp0 = xb + (size_t)tok0 * 1024;

  for (int k0 = 0; k0 < 1024; k0 += 64) {
    __syncthreads();
    const u16* wTp = wTp0 + k0;
    #pragma unroll
    for (int j = 0; j < 5; j++) {
      int ch = wv * 320 + j * 64 + l;
      int row = ch >> 3, part = ch & 7;
      gld16(wTp + (size_t)row * 1024 + ((part * 8) ^ ((row & 7) * 8)),
            &bsB[(wv * 320 + j * 64) * 8]);
    }
    const u16* xbp = xbp0 + k0;
    #pragma unroll
    for (int j = 0; j < 2; j++) {
      int ch = wv * 128 + j * 64 + l;
      int row = ch >> 3, part = ch & 7;
      gld16(xbp + (size_t)row * 1024 + ((part * 8) ^ ((row & 7) * 8)),
            &bsA[(wv * 128 + j * 64) * 8]);
    }
    __syncthreads();

    #pragma unroll
    for (int kk = 0; kk < 2; kk++) {
      int off = (kk * 32 + g * 8) ^ ((c & 7) * 8);
      s16x8 a = *reinterpret_cast<const s16x8*>(&bsA[(wv * 16 + c) * 64 + off]);
      #pragma unroll
      for (int nt = 0; nt < 20; nt++) {
        s16x8 b = *reinterpret_cast<const s16x8*>(&bsB[(nt * 16 + c) * 64 + off]);
        acc[nt] = mfma16(a, b, acc[nt]);
      }
    }
  }

  const int* eps = (s == 0) ? eps_d : eps_s;
  const float* w3 = (s == 0) ? sd3 : ss3;
  float scale = (s == 0) ? 0.125f : 1.0f;
  u16* dst = (s == 0) ? qw : (s == 1 ? kw : vw);
  #pragma unroll
  for (int r = 0; r < 4; r++) {
    int tokr = tok0 + wv * 16 + g * 4 + r;
    int base = (tokr * 8 + h) * 3;
    int e0 = eps[base], e1 = eps[base + 1], e2 = eps[base + 2];
    float w0 = w3[base], w1 = w3[base + 1], w2 = w3[base + 2];
    float we[5];
    #pragma unroll
    for (int e = 0; e < 5; e++)
      we[e] = (e0 == e ? w0 : 0.f) + (e1 == e ? w1 : 0.f) + (e2 == e ? w2 : 0.f);
    int b = tokr >> 11, t = tokr & 2047;
    size_t obase = (((size_t)b * 8 + h) * 2048 + t) * 64;
    #pragma unroll
    for (int dh = 0; dh < 4; dh++) {
      float vq = 0.f;
      #pragma unroll
      for (int e = 0; e < 5; e++) vq += we[e] * acc[e * 4 + dh][r];
      dst[obase + dh * 16 + c] = f2bf(vq * scale);
    }
  }
}

// (B,H,T,D) -> (B,H,D,T') with T' mu-permuted inside each 32-key tile:
// storage position p(k) = 8*((k&15)>>2) + (k&3) + (k>=16 ? 4 : 0).
// A 16B read at tile+8g then holds keys {4g..4g+3, 16+4g..16+4g+3} -- the
// exact B-fragment positional map used by k_attn's PV MFMA.
__global__ void k_trv(const u16* __restrict__ vw, u16* __restrict__ vT) {
  int bh = blockIdx.z;
  int t0 = blockIdx.x * 32, d0 = blockIdx.y * 32;
  __shared__ u16 tile[32][33];
  const u16* src = vw + (size_t)bh * 2048 * 64;
  u16* dst = vT + (size_t)bh * 64 * 2048;
  int tx = threadIdx.x, ty = threadIdx.y;
  #pragma unroll
  for (int i = 0; i < 4; i++)
    tile[ty + 8 * i][tx] = src[(size_t)(t0 + ty + 8 * i) * 64 + d0 + tx];
  __syncthreads();
  int p = 8 * ((tx & 15) >> 2) + (tx & 3) + ((tx >= 16) ? 4 : 0);
  #pragma unroll
  for (int i = 0; i < 4; i++)
    dst[(size_t)(d0 + ty + 8 * i) * 2048 + t0 + p] = tile[tx][ty + 8 * i];
}

// ---------- flash attention: LDS-staged K/V (k_proj structure) ----------
// grid (32, 16), block 256 = 4 waves; wave wq owns q-rows [q0+wq*16, +16).
// Per 128-key step: stage K[128][64] + mu-permuted V[64][128] to LDS via
// gld16 (linear dest, XOR-pre-swizzled SOURCE columns), barrier, then each
// wave: 4 x {4 QK MFMA -> exp/pack -> 4 PV MFMA} = 32 MFMA per barrier pair.
// Reads apply the same XOR -> free 2-way bank aliasing. No split-KV.
__launch_bounds__(256)
__global__ void k_attn(const u16* __restrict__ qw, const u16* __restrict__ kw,
                       const u16* __restrict__ vT, u16* __restrict__ ow) {
  int bh = blockIdx.y;
  int b = bh >> 3, h = bh & 7;
  int q0 = blockIdx.x * 64;
  int wv = threadIdx.x >> 6, l = threadIdx.x & 63;
  int g = l >> 4, c = l & 15;
  const u16* qp = qw + (size_t)bh * 2048 * 64;
  const u16* kp = kw + (size_t)bh * 2048 * 64;
  const u16* vp = vT + (size_t)bh * 64 * 2048;
  __shared__ alignas(16) u16 Kl[128 * 64];   // 16 KB, [key][d] linear
  __shared__ alignas(16) u16 Vl[64 * 128];   // 16 KB, [d][key'] linear (mu order)

  s16x8 qa0 = ld8(qp + (size_t)(q0 + wv * 16 + c) * 64 + 0 + 8 * g);
  s16x8 qa1 = ld8(qp + (size_t)(q0 + wv * 16 + c) * 64 + 32 + 8 * g);

  f32x4 o[4];
  #pragma unroll
  for (int i = 0; i < 4; i++) o[i] = (f32x4){0.f, 0.f, 0.f, 0.f};
  float ssum = 0.f;   // denom partial for q = c

  for (int kt = 0; kt < 2048; kt += 128) {
    __syncthreads();
    // stage K: 1024 chunks (row=ch>>3, slot=ch&7), source col-chunk slot^(row&7)
    #pragma unroll
    for (int j = 0; j < 4; j++) {
      int ch = (wv * 4 + j) * 64 + l;
      int row = ch >> 3, sl = ch & 7;
      gld16(kp + (size_t)(kt + row) * 64 + ((sl ^ (row & 7)) * 8),
            &Kl[(wv * 4 + j) * 64 * 8]);
    }
    // stage V: 1024 chunks (d=ch>>4, slot=ch&15), source col-chunk slot^(d&15)
    #pragma unroll
    for (int j = 0; j < 4; j++) {
      int ch = (wv * 4 + j) * 64 + l;
      int d = ch >> 4, sl = ch & 15;
      gld16(vp + (size_t)d * 2048 + kt + ((sl ^ (d & 15)) * 8),
            &Vl[(wv * 4 + j) * 64 * 8]);
    }
    __syncthreads();

    #pragma unroll
    for (int kk = 0; kk < 4; kk++) {
      int r0 = kk * 32 + c, r1 = kk * 32 + 16 + c;        // K rows (keys)
      int c7 = c & 7;
      s16x8 ka0 = *reinterpret_cast<const s16x8*>(&Kl[r0 * 64 + ((0 + g) ^ c7) * 8]);
      s16x8 ka1 = *reinterpret_cast<const s16x8*>(&Kl[r0 * 64 + ((4 + g) ^ c7) * 8]);
      s16x8 kc0 = *reinterpret_cast<const s16x8*>(&Kl[r1 * 64 + ((0 + g) ^ c7) * 8]);
      s16x8 kc1 = *reinterpret_cast<const s16x8*>(&Kl[r1 * 64 + ((4 + g) ^ c7) * 8]);

      f32x4 s0 = (f32x4){0.f, 0.f, 0.f, 0.f};
      f32x4 s1 = (f32x4){0.f, 0.f, 0.f, 0.f};
      s0 = mfma16(ka0, qa0, s0);
      s0 = mfma16(ka1, qa1, s0);
      s1 = mfma16(kc0, qa0, s1);
      s1 = mfma16(kc1, qa1, s1);

      float p00 = __expf(s0[0]), p01 = __expf(s0[1]);
      float p02 = __expf(s0[2]), p03 = __expf(s0[3]);
      float p10 = __expf(s1[0]), p11 = __expf(s1[1]);
      float p12 = __expf(s1[2]), p13 = __expf(s1[3]);
      ssum += (p00 + p01) + (p02 + p03) + (p10 + p11) + (p12 + p13);

      uint4 pw = make_uint4(pk2(p00, p01), pk2(p02, p03),
                            pk2(p10, p11), pk2(p12, p13));
      s16x8 pa = __builtin_bit_cast(s16x8, pw);

      #pragma unroll
      for (int nt = 0; nt < 4; nt++) {
        int d = nt * 16 + c;
        s16x8 vb = *reinterpret_cast<const s16x8*>(&Vl[d * 128 + (((kk * 4 + g) ^ (d & 15)) * 8)]);
        o[nt] = mfma16(pa, vb, o[nt]);
      }
    }
  }

  // ssum is per-(g,c) partial over its key slots; reduce over g (bits 4,5).
  ssum += __shfl_xor(ssum, 16, 64);
  ssum += __shfl_xor(ssum, 32, 64);
  // lane (g,c) holds denom(q=c); o rows are q = g*4+r -> fetch via shfl.
  #pragma unroll
  for (int r = 0; r < 4; r++) {
    float sm = __shfl(ssum, g * 4 + r, 64);
    float inv = 1.f / sm;
    int t = q0 + wv * 16 + g * 4 + r;
    #pragma unroll
    for (int nt = 0; nt < 4; nt++)
      ow[((size_t)(b * 2048 + t)) * 512 + h * 64 + nt * 16 + c] = f2bf(o[nt][r] * inv);
  }
}

// ---------- output projection ----------
__launch_bounds__(512)
__global__ void k_oproj(const u16* __restrict__ ow, const u16* __restrict__ woT,
                        const float* __restrict__ biasum, float* __restrict__ out) {
  int t0 = blockIdx.x * 128, f0 = blockIdx.y * 64;
  int wv = threadIdx.x >> 6, l = threadIdx.x & 63;
  int g = l >> 4, c = l & 15;
  f32x4 acc[4];
  #pragma unroll
  for (int i = 0; i < 4; i++) acc[i] = (f32x4){0.f, 0.f, 0.f, 0.f};
  for (int k0 = 0; k0 < 512; k0 += 32) {
    s16x8 a = ld8(ow + (size_t)(t0 + wv * 16 + c) * 512 + k0 + 8 * g);
    #pragma unroll
    for (int nt = 0; nt < 4; nt++) {
      s16x8 bfr = ld8(woT + (size_t)(f0 + nt * 16 + c) * 512 + k0 + 8 * g);
      acc[nt] = mfma16(a, bfr, acc[nt]);
    }
  }
  #pragma unroll
  for (int r = 0; r < 4; r++) {
    int t = t0 + wv * 16 + g * 4 + r;
    #pragma unroll
    for (int nt = 0; nt < 4; nt++) {
      int f = f0 + nt * 16 + c;
      out[(size_t)t * 1024 + f] = acc[nt][r] + biasum[f];
    }
  }
}

extern "C" void kernel_launch(void* const* d_in, const int* in_sizes, int n_in,
                              void* d_out, int out_size, void* d_ws, size_t ws_size,
                              hipStream_t stream) {
  const float* x    = (const float*)d_in[0];
  const float* w_q  = (const float*)d_in[1];
  const float* w_kv = (const float*)d_in[2];
  const float* w_s  = (const float*)d_in[3];
  const float* w_d  = (const float*)d_in[4];
  const float* w_ow = (const float*)d_in[5];
  const float* w_ob = (const float*)d_in[6];
  float* out = (float*)d_out;

  char* ws = (char*)d_ws;
  size_t o = 0;
  u16* xb     = (u16*)(ws + o); o += (size_t)NTOK * DIMc * 2;
  u16* wT     = (u16*)(ws + o); o += (size_t)3 * NQ * DIMc * 2;
  u16* woT    = (u16*)(ws + o); o += (size_t)1024 * 512 * 2;
  float* bsum = (float*)(ws + o); o += 4096;
  float* wsdT = (float*)(ws + o); o += (size_t)80 * 1024 * 4;
  int* eps_s  = (int*)(ws + o); o += (size_t)NTOK * 8 * 3 * 4;
  int* eps_d  = (int*)(ws + o); o += (size_t)NTOK * 8 * 3 * 4;
  float* ss3  = (float*)(ws + o); o += (size_t)NTOK * 8 * 3 * 4;
  float* sd3  = (float*)(ws + o); o += (size_t)NTOK * 8 * 3 * 4;
  u16* qw     = (u16*)(ws + o); o += (size_t)NTOK * 512 * 2;
  u16* kw     = (u16*)(ws + o); o += (size_t)NTOK * 512 * 2;
  u16* vw     = (u16*)(ws + o); o += (size_t)NTOK * 512 * 2;
  u16* vTw    = (u16*)(ws + o); o += (size_t)NTOK * 512 * 2;
  u16* oww    = (u16*)(ws + o); o += (size_t)NTOK * 512 * 2;

  k_cvt_x<<<4096, 256, 0, stream>>>(x, xb);
  k_tr_w<<<dim3(240, 32), dim3(32, 8), 0, stream>>>(w_q, w_kv, wT);
  k_tr_wo<<<1024, 64, 0, stream>>>(w_ow, woT);
  k_bias<<<4, 256, 0, stream>>>(w_ob, bsum);
  k_tr_wsd<<<80, 256, 0, stream>>>(w_s, w_d, wsdT);
  k_scores<<<512, 320, 0, stream>>>(x, wsdT, eps_s, eps_d, ss3, sd3);
  k_proj<<<dim3(32, 8, 3), 512, 0, stream>>>(xb, wT, eps_d, eps_s, sd3, ss3, qw, kw, vw);
  k_trv<<<dim3(64, 2, 16), dim3(32, 8), 0, stream>>>(vw, vTw);
  k_attn<<<dim3(32, 16), 256, 0, stream>>>(qw, kw, vTw, oww);
  k_oproj<<<dim3(32, 16), 512, 0, stream>>>(oww, woT, bsum, out);
}